// Round 1
// baseline (298.587 us; speedup 1.0000x reference)
//
#include <hip/hip_runtime.h>
#include <hip/hip_bf16.h>
#include <math.h>

// CRF loss on MI355X.
//   emit = feat @ W^T + b           (bf16 MFMA GEMM, H padded 52->64)
//   forward algorithm               (linear-space chunked matrix scan, bf16 MFMA)
//   gold score                      (gather/reduce)
//   out = mean(fwd - gold)          (atomicAdd into memset-zeroed d_out)
//
// Linear-space trick: step is scores' = log(diag(e^emit)*exp(T)*e^scores).
// A chunk of 64 steps is a product of 64 matrices M_t = diag(e^emit_t)*exp(Tpad);
// exp(Tpad) is a CONSTANT MFMA A-operand held in registers. Per-step power-of-2
// rescale (exact; integer exponent accumulated) keeps fp32/bf16 in range.
// Padding: Tpad[i][j>=52] = NEG (exp->0, padded sources never feed real rows);
// Tpad[i>=52][j<52] = 0 (padded rows stay finite, excluded at the end by
// exp(TSTOP[j>=52]) = 0). Masks supported for {0,1} (the harness inputs are all 1):
// mask==0 => step skipped (identity matrix).

#define NEGV   (-100000000.0f)
#define BB     64
#define TT     512
#define FF     1024
#define HH     52
#define HP     64
#define S_START 50
#define S_STOP  51
#define NCHUNK 8
#define CLEN   (TT / NCHUNK)   // 64

typedef __bf16 bf16x8 __attribute__((ext_vector_type(8)));
typedef __bf16 bf16x4 __attribute__((ext_vector_type(4)));
typedef float  f32x4  __attribute__((ext_vector_type(4)));

// ---------------- ws layout (bytes), total ~16.2 MiB ----------------
#define WS_EMIT   0u          // fp32 [B*T][HP]            8,388,608
#define WS_CHUNK  8388608u    // fp32 [B*NCHUNK][HP*HP]    8,388,608
#define WS_WBF    16777216u   // bf16 [HP][FF]               131,072
#define WS_GOLD   16908288u   // fp32 [BB]
#define WS_CEXP   16908544u   // fp32 [B*NCHUNK]

// ---- W fp32 -> bf16, padded rows 52..63 = 0 ----
__global__ __launch_bounds__(256) void k_prep(const float* __restrict__ W,
                                              __bf16* __restrict__ wbf) {
  int n = blockIdx.x;  // 0..63
  for (int k = threadIdx.x; k < FF; k += 256) {
    float v = (n < HH) ? W[n * FF + k] : 0.0f;
    wbf[n * FF + k] = (__bf16)v;
  }
}

// ---- emit GEMM: 512 blocks, each 64 rows x 64 cols, K=1024 in 16 chunks ----
// LDS A-tile row stride = 72 shorts (144 B = 36 words): ds_read_b128 frag reads
// tile all 32 banks uniformly (8 lanes per 4-bank group = optimal for 1KB/instr).
__global__ __launch_bounds__(256) void k_emit(const float* __restrict__ feat,
                                              const __bf16* __restrict__ wbf,
                                              const float* __restrict__ bias,
                                              float* __restrict__ emit) {
  __shared__ __align__(16) __bf16 Asm[64 * 72];
  const int tid = threadIdx.x;
  const int wv = tid >> 6;
  const int l  = tid & 63;
  const int lm = l & 15;
  const int q  = l >> 4;
  const size_t row0 = (size_t)blockIdx.x * 64;

  float bn[4];
#pragma unroll
  for (int nt = 0; nt < 4; ++nt) {
    int n = nt * 16 + lm;
    bn[nt] = (n < HH) ? bias[n] : 0.0f;
  }

  f32x4 acc[4] = {};

  const int srow = tid >> 4;        // 0..15
  const int scol = (tid & 15) * 4;  // 0..60

  for (int kc = 0; kc < 16; ++kc) {
    const int k0 = kc * 64;
    if (kc) __syncthreads();
#pragma unroll
    for (int p = 0; p < 4; ++p) {
      int r = srow + p * 16;
      f32x4 v = *(const f32x4*)(feat + (row0 + r) * FF + k0 + scol);
      bf16x4 bv;
#pragma unroll
      for (int j = 0; j < 4; ++j) bv[j] = (__bf16)v[j];
      *(bf16x4*)&Asm[r * 72 + scol] = bv;
    }
    __syncthreads();
#pragma unroll
    for (int kk = 0; kk < 2; ++kk) {
      bf16x8 af = *(const bf16x8*)&Asm[(wv * 16 + lm) * 72 + kk * 32 + q * 8];
#pragma unroll
      for (int nt = 0; nt < 4; ++nt) {
        bf16x8 bfr = *(const bf16x8*)(wbf + (size_t)(nt * 16 + lm) * FF + k0 + kk * 32 + q * 8);
        acc[nt] = __builtin_amdgcn_mfma_f32_16x16x32_bf16(af, bfr, acc[nt], 0, 0, 0);
      }
    }
  }

#pragma unroll
  for (int nt = 0; nt < 4; ++nt) {
#pragma unroll
    for (int rr = 0; rr < 4; ++rr) {
      size_t m = row0 + wv * 16 + q * 4 + rr;   // D: row = quad*4+reg, col = lane&15
      emit[m * HP + nt * 16 + lm] = acc[nt][rr] + bn[nt];
    }
  }
}

// ---- gold score ----
__global__ __launch_bounds__(256) void k_gold(const float* __restrict__ emit,
                                              const int* __restrict__ tags,
                                              const float* __restrict__ masks,
                                              const float* __restrict__ trans,
                                              float* __restrict__ gold) {
  const int b = blockIdx.x;
  const int tid = threadIdx.x;
  float acc = 0.f, msum = 0.f;
  for (int t = tid; t < TT; t += 256) {
    int tg = tags[b * TT + t];
    int pv = (t == 0) ? S_START : tags[b * TT + t - 1];
    float m = masks[b * TT + t];
    float e = emit[((size_t)b * TT + t) * HP + tg];
    float tr = trans[tg * HH + pv];
    acc += (e + tr) * m;
    msum += m;
  }
#pragma unroll
  for (int d = 32; d > 0; d >>= 1) {
    acc += __shfl_xor(acc, d);
    msum += __shfl_xor(msum, d);
  }
  __shared__ float ra[4], rm[4];
  if ((tid & 63) == 0) { ra[tid >> 6] = acc; rm[tid >> 6] = msum; }
  __syncthreads();
  if (tid == 0) {
    float tot = ra[0] + ra[1] + ra[2] + ra[3];
    float ms  = rm[0] + rm[1] + rm[2] + rm[3];
    int lp = (int)(ms + 0.5f);
    int lt = (lp == 0) ? S_START : tags[b * TT + lp - 1];
    gold[b] = tot + trans[S_STOP * HH + lt];
  }
}

// ---- chunk transfer-matrix products: 512 blocks (b,c), 64 MFMA steps each ----
__global__ __launch_bounds__(256) void k_chunks(const float* __restrict__ emit,
                                                const float* __restrict__ trans,
                                                const float* __restrict__ masks,
                                                float* __restrict__ chunks,
                                                float* __restrict__ cexp) {
  const int blk = blockIdx.x;          // b*NCHUNK + c
  const int b = blk >> 3, c = blk & 7;
  const int tid = threadIdx.x;
  const int wv = tid >> 6;
  const int l = tid & 63;
  const int lm = l & 15;
  const int q = l >> 4;

  __shared__ __align__(16) __bf16 PT[2][64 * 72];  // P transposed, stride 72
  __shared__ float wmax[2][4];

  // constant A-frags: exp(Tpad[m][k]) for this wave's 16-row stripe
  const int m = wv * 16 + lm;
  bf16x8 afrag[2];
#pragma unroll
  for (int kk = 0; kk < 2; ++kk) {
#pragma unroll
    for (int j = 0; j < 8; ++j) {
      int k = kk * 32 + q * 8 + j;
      float tv;
      if (k >= HH) tv = NEGV;          // padded source column -> weight 0
      else if (m >= HH) tv = 0.0f;     // padded dest row -> weight 1 (stays finite)
      else tv = trans[m * HH + k];
      afrag[kk][j] = (__bf16)__expf(tv);
    }
  }

  // P = I (identity is symmetric, transpose-safe)
  for (int idx = tid; idx < 4096; idx += 256) {
    int n = idx >> 6, mm = idx & 63;
    PT[0][n * 72 + mm] = (__bf16)((n == mm) ? 1.0f : 0.0f);
  }
  if (tid < 4) wmax[0][tid] = 1.0f;
  __syncthreads();

  const float* eb = emit + ((size_t)b * TT + c * CLEN) * HP + wv * 16 + q * 4;
  const float* mb = masks + b * TT + c * CLEN;
  f32x4 epf = *(const f32x4*)(eb);
  float mpf = mb[0];

  int pb = 0;
  int eacc = 0;

  for (int t = 0; t < CLEN; ++t) {
    f32x4 ecur = epf;
    float mcur = mpf;            // block-uniform -> branch is uniform
    int tn = (t + 1 < CLEN) ? t + 1 : t;
    epf = *(const f32x4*)(eb + (size_t)tn * HP);  // prefetch next step
    mpf = mb[tn];

    if (mcur != 0.0f) {
      // 1-step-lagged power-of-2 scale (exact): bring stored max toward 1.
      float pm = fmaxf(fmaxf(wmax[pb][0], wmax[pb][1]),
                       fmaxf(wmax[pb][2], wmax[pb][3]));
      int r = ilogbf(pm);
      const int nb = pb ^ 1;

      f32x4 acc[4] = {};
#pragma unroll
      for (int kk = 0; kk < 2; ++kk) {
#pragma unroll
        for (int nt = 0; nt < 4; ++nt) {
          bf16x8 bfr = *(const bf16x8*)&PT[pb][(nt * 16 + lm) * 72 + kk * 32 + q * 8];
          acc[nt] = __builtin_amdgcn_mfma_f32_16x16x32_bf16(afrag[kk], bfr, acc[nt], 0, 0, 0);
        }
      }
      float s[4];
#pragma unroll
      for (int rr = 0; rr < 4; ++rr) s[rr] = ldexpf(__expf(ecur[rr]), -r);

      float mx = 0.0f;
#pragma unroll
      for (int nt = 0; nt < 4; ++nt) {
        bf16x4 w4;
#pragma unroll
        for (int rr = 0; rr < 4; ++rr) {
          float v = acc[nt][rr] * s[rr];   // all entries >= 0
          mx = fmaxf(mx, v);
          w4[rr] = (__bf16)v;
        }
        // PT'[n][m], 4 consecutive m -> 8B store
        *(bf16x4*)&PT[nb][(nt * 16 + lm) * 72 + wv * 16 + q * 4] = w4;
      }
#pragma unroll
      for (int d = 1; d < 64; d <<= 1) mx = fmaxf(mx, __shfl_xor(mx, d));
      if (l == 0) wmax[nb][wv] = mx;      // wave covers its full 16-row stripe
      eacc += r;
      __syncthreads();
      pb = nb;
    }
  }

  // store P[i][j] row-major + accumulated exponent
  for (int idx = tid; idx < 4096; idx += 256) {
    int i = idx >> 6, j = idx & 63;
    chunks[(size_t)blk * 4096 + idx] = (float)PT[pb][j * 72 + i];
  }
  if (tid == 0) cexp[blk] = (float)eacc;
}

// ---- combine: 64 blocks x 1 wave; 8 matvecs + final logsumexp + atomic mean ----
__global__ __launch_bounds__(64) void k_combine(const float* __restrict__ chunks,
                                                const float* __restrict__ cexp,
                                                const float* __restrict__ trans,
                                                const float* __restrict__ gold,
                                                float* __restrict__ out) {
  const int b = blockIdx.x;
  const int l = threadIdx.x;   // 0..63 = state i
  __shared__ float vsh[64];
  float v = (l == S_START) ? 1.0f : 0.0f;
  float esum = 0.0f;
  const float LN2 = 0.6931471805599453f;

  for (int cc = 0; cc < NCHUNK; ++cc) {
    vsh[l] = v;
    __syncthreads();
    const f32x4* Mr = (const f32x4*)(chunks + ((size_t)b * NCHUNK + cc) * 4096 + l * 64);
    float u = 0.0f;
#pragma unroll
    for (int jj = 0; jj < 16; ++jj) {
      f32x4 mv = Mr[jj];
      u += mv[0] * vsh[jj * 4 + 0] + mv[1] * vsh[jj * 4 + 1] +
           mv[2] * vsh[jj * 4 + 2] + mv[3] * vsh[jj * 4 + 3];
    }
    esum += cexp[b * NCHUNK + cc] * LN2;
    float mxx = u;
#pragma unroll
    for (int d = 1; d < 64; d <<= 1) mxx = fmaxf(mxx, __shfl_xor(mxx, d));
    if (mxx > 0.0f) {
      int ee = ilogbf(mxx);
      u = ldexpf(u, -ee);
      esum += (float)ee * LN2;
    }
    v = u;
    __syncthreads();
  }

  float ts = (l < HH) ? trans[S_STOP * HH + l] : NEGV;  // exp(NEG)=0 excludes pads & STOP
  float contrib = v * __expf(ts);
#pragma unroll
  for (int d = 1; d < 64; d <<= 1) contrib += __shfl_xor(contrib, d);
  if (l == 0) {
    float fwd = __logf(contrib) + esum;
    atomicAdd(out, (fwd - gold[b]) * (1.0f / 64.0f));
  }
}

extern "C" void kernel_launch(void* const* d_in, const int* in_sizes, int n_in,
                              void* d_out, int out_size, void* d_ws, size_t ws_size,
                              hipStream_t stream) {
  (void)in_sizes; (void)n_in; (void)out_size; (void)ws_size;
  const float* feat  = (const float*)d_in[0];
  const float* W     = (const float*)d_in[1];
  const float* bias  = (const float*)d_in[2];
  const float* trans = (const float*)d_in[3];
  const float* masks = (const float*)d_in[4];
  const int*   tags  = (const int*)d_in[5];

  char* ws = (char*)d_ws;
  float*  emit   = (float*)(ws + WS_EMIT);
  float*  chunks = (float*)(ws + WS_CHUNK);
  __bf16* wbf    = (__bf16*)(ws + WS_WBF);
  float*  gold   = (float*)(ws + WS_GOLD);
  float*  cexp   = (float*)(ws + WS_CEXP);

  hipMemsetAsync(d_out, 0, sizeof(float), stream);
  k_prep<<<HP, 256, 0, stream>>>(W, wbf);
  k_emit<<<(BB * TT) / 64, 256, 0, stream>>>(feat, wbf, bias, emit);
  k_gold<<<BB, 256, 0, stream>>>(emit, tags, masks, trans, gold);
  k_chunks<<<BB * NCHUNK, 256, 0, stream>>>(emit, trans, masks, chunks, cexp);
  k_combine<<<BB, 64, 0, stream>>>(chunks, cexp, trans, gold, (float*)d_out);
}

// Round 2
// 280.922 us; speedup vs baseline: 1.0629x; 1.0629x over previous
//
#include <hip/hip_runtime.h>
#include <hip/hip_bf16.h>
#include <math.h>

// CRF loss on MI355X.
//   emit = feat @ W^T + b         (bf16 MFMA, no-LDS A-frags direct from global)
//   forward algorithm             (wave-autonomous chunked matrix scan, bf16 MFMA)
//   gold score                    (gather/reduce)
//   out = mean(fwd - gold)
//
// Scan: chunk of 32 steps per WAVE (1024 wave-chunks = 1 wave/SIMD, no barriers).
// Each step: P <- diag(exp(emit_t - 7ln2 - r ln2)) * exp(Tpad) * P, all in one
// wave (32 MFMA 16x16x32_bf16, afrag const in regs, P bf16 in wave-private LDS).
// Fixed 2^-7/step shift (folded into exp arg, free) + exact power-of-2 rescale
// every 8 steps (wave shuffle max). Integer exponent accumulated in eacc.
// Padding: Tpad[i][j>=52]=NEG (exp->0: pads never feed real rows);
// Tpad[i>=52][j<52]=0 (pad rows finite, excluded by exp(TSTOP[j>=52])=0).

#define NEGV   (-100000000.0f)
#define BB     64
#define TT     512
#define FF     1024
#define HH     52
#define HP     64
#define S_START 50
#define S_STOP  51
#define NCH    16            // chunks per batch
#define CLEN   (TT / NCH)    // 32 steps per chunk

typedef __bf16 bf16x8 __attribute__((ext_vector_type(8)));
typedef __bf16 bf16x4 __attribute__((ext_vector_type(4)));
typedef float  f32x4  __attribute__((ext_vector_type(4)));

// ---------------- ws layout (bytes) ----------------
#define WS_EMIT   0u           // fp32 [B*T][HP]                  8,388,608
#define WS_CHUNK  8388608u     // fp32 [1024][16][64][4] (jj,i,jr) 16,777,216
#define WS_WBF    25165824u    // bf16 [HP][FF]                     131,072
#define WS_GOLD   25296896u    // fp32 [BB]
#define WS_CEXP   25297152u    // fp32 [1024]

// ---- W fp32 -> bf16, padded rows 52..63 = 0 ----
__global__ __launch_bounds__(256) void k_prep(const float* __restrict__ W,
                                              __bf16* __restrict__ wbf) {
  int n = blockIdx.x;  // 0..63
  for (int k = threadIdx.x; k < FF; k += 256) {
    float v = (n < HH) ? W[n * FF + k] : 0.0f;
    wbf[n * FF + k] = (__bf16)v;
  }
}

// ---- emit GEMM: 512 blocks x 4 waves; A-frags straight from global, no LDS ----
// Lane (q,lm) of wave wv reads A row (row0+wv*16+lm), k = kc*64+kk*32+q*8..+7.
// 4 q-lanes of one row cover contiguous 128B per kk -> L1/L2 friendly.
__global__ __launch_bounds__(256) void k_emit(const float* __restrict__ feat,
                                              const __bf16* __restrict__ wbf,
                                              const float* __restrict__ bias,
                                              float* __restrict__ emit) {
  const int tid = threadIdx.x;
  const int wv = tid >> 6;
  const int l  = tid & 63;
  const int lm = l & 15;
  const int q  = l >> 4;
  const size_t row0 = (size_t)blockIdx.x * 64;
  const float* fr = feat + (row0 + wv * 16 + lm) * FF;

  float bn[4];
#pragma unroll
  for (int nt = 0; nt < 4; ++nt) {
    int n = nt * 16 + lm;
    bn[nt] = (n < HH) ? bias[n] : 0.0f;
  }

  f32x4 acc[4] = {};

  // register prefetch pipeline over 16 k-chunks
  f32x4 xa[2][2];
#pragma unroll
  for (int kk = 0; kk < 2; ++kk)
#pragma unroll
    for (int h = 0; h < 2; ++h)
      xa[kk][h] = *(const f32x4*)(fr + kk * 32 + q * 8 + h * 4);

  for (int kc = 0; kc < 16; ++kc) {
    bf16x8 af[2];
#pragma unroll
    for (int kk = 0; kk < 2; ++kk)
#pragma unroll
      for (int j = 0; j < 4; ++j) {
        af[kk][j]     = (__bf16)xa[kk][0][j];
        af[kk][4 + j] = (__bf16)xa[kk][1][j];
      }
    f32x4 xn[2][2];
    if (kc < 15) {
      const float* nf = fr + (kc + 1) * 64;
#pragma unroll
      for (int kk = 0; kk < 2; ++kk)
#pragma unroll
        for (int h = 0; h < 2; ++h)
          xn[kk][h] = *(const f32x4*)(nf + kk * 32 + q * 8 + h * 4);
    }
    const int k0 = kc * 64;
#pragma unroll
    for (int kk = 0; kk < 2; ++kk)
#pragma unroll
      for (int nt = 0; nt < 4; ++nt) {
        bf16x8 bfr = *(const bf16x8*)(wbf + (size_t)(nt * 16 + lm) * FF + k0 + kk * 32 + q * 8);
        acc[nt] = __builtin_amdgcn_mfma_f32_16x16x32_bf16(af[kk], bfr, acc[nt], 0, 0, 0);
      }
#pragma unroll
    for (int kk = 0; kk < 2; ++kk)
#pragma unroll
      for (int h = 0; h < 2; ++h)
        xa[kk][h] = xn[kk][h];
  }

#pragma unroll
  for (int nt = 0; nt < 4; ++nt) {
#pragma unroll
    for (int rr = 0; rr < 4; ++rr) {
      size_t m = row0 + wv * 16 + q * 4 + rr;   // D: row = quad*4+reg, col = lane&15
      emit[m * HP + nt * 16 + lm] = acc[nt][rr] + bn[nt];
    }
  }
}

// ---- gold score ----
__global__ __launch_bounds__(256) void k_gold(const float* __restrict__ emit,
                                              const int* __restrict__ tags,
                                              const float* __restrict__ masks,
                                              const float* __restrict__ trans,
                                              float* __restrict__ gold) {
  const int b = blockIdx.x;
  const int tid = threadIdx.x;
  float acc = 0.f, msum = 0.f;
  for (int t = tid; t < TT; t += 256) {
    int tg = tags[b * TT + t];
    int pv = (t == 0) ? S_START : tags[b * TT + t - 1];
    float m = masks[b * TT + t];
    float e = emit[((size_t)b * TT + t) * HP + tg];
    float tr = trans[tg * HH + pv];
    acc += (e + tr) * m;
    msum += m;
  }
#pragma unroll
  for (int d = 32; d > 0; d >>= 1) {
    acc += __shfl_xor(acc, d);
    msum += __shfl_xor(msum, d);
  }
  __shared__ float ra[4], rm[4];
  if ((tid & 63) == 0) { ra[tid >> 6] = acc; rm[tid >> 6] = msum; }
  __syncthreads();
  if (tid == 0) {
    float tot = ra[0] + ra[1] + ra[2] + ra[3];
    float ms  = rm[0] + rm[1] + rm[2] + rm[3];
    int lp = (int)(ms + 0.5f);
    int lt = (lp == 0) ? S_START : tags[b * TT + lp - 1];
    gold[b] = tot + trans[S_STOP * HH + lt];
  }
}

// ---- wave-autonomous chunk products: 256 blocks x 4 waves = 1024 wave-chunks ----
__global__ __launch_bounds__(256, 1) void k_chunks(const float* __restrict__ emit,
                                                   const float* __restrict__ trans,
                                                   const float* __restrict__ masks,
                                                   float* __restrict__ chunks,
                                                   float* __restrict__ cexp) {
  const int tid = threadIdx.x;
  const int wv = tid >> 6;
  const int l  = tid & 63;
  const int lm = l & 15;
  const int q  = l >> 4;
  const int chunk = blockIdx.x * 4 + wv;   // 0..1023
  const int b = chunk >> 4, c = chunk & 15;

  // wave-private P^T buffer: PT[n*72+m] = P[m][n]; stride 72 keeps b128 reads
  // 16B-aligned (144B rows) and conflicts at 2-way (free) within 16-lane phases.
  __shared__ __align__(16) __bf16 PTall[4][64 * 72];
  __bf16* pt = PTall[wv];

  // constant A = exp(Tpad): full 64 rows in regs (4 m-tiles x 2 k-chunks)
  bf16x8 afrag[4][2];
#pragma unroll
  for (int mt = 0; mt < 4; ++mt)
#pragma unroll
    for (int kk = 0; kk < 2; ++kk)
#pragma unroll
      for (int j = 0; j < 8; ++j) {
        int m = mt * 16 + lm, k = kk * 32 + q * 8 + j;
        float tv = (k >= HH) ? NEGV : ((m >= HH) ? 0.0f : trans[m * HH + k]);
        afrag[mt][kk][j] = (__bf16)__expf(tv);
      }

  // P = I (wave-private, in-order LDS: no barrier needed anywhere)
  for (int idx = l; idx < 4096; idx += 64) {
    int n = idx >> 6, mm = idx & 63;
    pt[n * 72 + mm] = (__bf16)((n == mm) ? 1.0f : 0.0f);
  }

  const float* eb = emit + ((size_t)(b * TT + c * CLEN)) * HP;
  const float* mb = masks + b * TT + c * CLEN;

  f32x4 ep[4];
#pragma unroll
  for (int mt = 0; mt < 4; ++mt) ep[mt] = *(const f32x4*)(eb + mt * 16 + q * 4);
  float mpf = mb[0];

  int eacc = 0, rpend = 0;
  const float LOG2E = 1.4426950408889634f;

  for (int t = 0; t < CLEN; ++t) {
    f32x4 ec[4];
#pragma unroll
    for (int mt = 0; mt < 4; ++mt) ec[mt] = ep[mt];
    float mcur = mpf;
    int tn = (t + 1 < CLEN) ? t + 1 : t;
#pragma unroll
    for (int mt = 0; mt < 4; ++mt)
      ep[mt] = *(const f32x4*)(eb + (size_t)tn * HP + mt * 16 + q * 4);
    mpf = mb[tn];

    if (mcur != 0.0f) {                       // wave-uniform
      float sh = (float)(7 + rpend);          // fixed 2^-7/step + pending rescale
      eacc += 7 + rpend;
      rpend = 0;
      float s[4][4];
#pragma unroll
      for (int mt = 0; mt < 4; ++mt)
#pragma unroll
        for (int rr = 0; rr < 4; ++rr)
          s[mt][rr] = __builtin_amdgcn_exp2f(fmaf(ec[mt][rr], LOG2E, -sh));

      // ALL reads before ALL writes (in-order LDS per wave => correct, no sync)
      bf16x8 bfr[2][4];
#pragma unroll
      for (int kk = 0; kk < 2; ++kk)
#pragma unroll
        for (int nt = 0; nt < 4; ++nt)
          bfr[kk][nt] = *(const bf16x8*)&pt[(nt * 16 + lm) * 72 + kk * 32 + q * 8];

      const bool trk = ((t & 7) == 7) && (t != CLEN - 1);
      float lmax = 0.0f;
      f32x4 zero = {};
#pragma unroll
      for (int mt = 0; mt < 4; ++mt) {
#pragma unroll
        for (int nt = 0; nt < 4; ++nt) {
          f32x4 a = __builtin_amdgcn_mfma_f32_16x16x32_bf16(afrag[mt][0], bfr[0][nt], zero, 0, 0, 0);
          a = __builtin_amdgcn_mfma_f32_16x16x32_bf16(afrag[mt][1], bfr[1][nt], a, 0, 0, 0);
          bf16x4 w4;
#pragma unroll
          for (int rr = 0; rr < 4; ++rr) {
            float v = a[rr] * s[mt][rr];
            if (trk) lmax = fmaxf(lmax, v);
            w4[rr] = (__bf16)v;
          }
          // PT'[n=nt*16+lm][m=mt*16+q*4 ..+3]
          *(bf16x4*)&pt[(nt * 16 + lm) * 72 + mt * 16 + q * 4] = w4;
        }
      }
      if (trk) {
#pragma unroll
        for (int d = 1; d < 64; d <<= 1) lmax = fmaxf(lmax, __shfl_xor(lmax, d));
        rpend = ilogbf(lmax);                 // exact pow2, applied next step
      }
    }
  }

  // dump in combine-friendly layout: out[jj*256 + i*4 + jr] = P[i][4jj+jr]
  for (int idx = l; idx < 4096; idx += 64) {
    int jj = idx >> 8, i = (idx >> 2) & 63, jr = idx & 3;
    chunks[(size_t)chunk * 4096 + idx] = (float)pt[(jj * 4 + jr) * 72 + i];
  }
  if (l == 0) cexp[chunk] = (float)eacc;
}

// ---- combine: 64 blocks x 1 wave; 16 matvecs + final logsumexp + atomic mean ----
__global__ __launch_bounds__(64) void k_combine(const float* __restrict__ chunks,
                                                const float* __restrict__ cexp,
                                                const float* __restrict__ trans,
                                                const float* __restrict__ gold,
                                                float* __restrict__ out) {
  const int b = blockIdx.x;
  const int l = threadIdx.x;   // 0..63 = state i
  __shared__ float vsh[64];
  float v = (l == S_START) ? 1.0f : 0.0f;
  float esum = 0.0f;
  const float LN2 = 0.6931471805599453f;

  for (int cc = 0; cc < NCH; ++cc) {
    vsh[l] = v;
    __syncthreads();
    const f32x4* M = (const f32x4*)(chunks + ((size_t)(b * NCH + cc)) * 4096);
    f32x4 u4 = {};
#pragma unroll
    for (int jj = 0; jj < 16; ++jj) {
      f32x4 m4 = M[jj * 64 + l];              // coalesced: 64 lanes x 16B
      const float* vj = &vsh[jj * 4];         // lane-uniform broadcast
      u4[0] += m4[0] * vj[0];
      u4[1] += m4[1] * vj[1];
      u4[2] += m4[2] * vj[2];
      u4[3] += m4[3] * vj[3];
    }
    float u = (u4[0] + u4[1]) + (u4[2] + u4[3]);
    esum += cexp[b * NCH + cc] * LN2;
    float mxx = u;
#pragma unroll
    for (int d = 1; d < 64; d <<= 1) mxx = fmaxf(mxx, __shfl_xor(mxx, d));
    if (mxx > 0.0f) {
      int ee = ilogbf(mxx);
      u = ldexpf(u, -ee);
      esum += (float)ee * LN2;
    }
    v = u;
    __syncthreads();
  }

  float ts = (l < HH) ? trans[S_STOP * HH + l] : NEGV;  // exp(NEG)=0 excludes pads
  float contrib = v * __expf(ts);
#pragma unroll
  for (int d = 1; d < 64; d <<= 1) contrib += __shfl_xor(contrib, d);
  if (l == 0) {
    float fwd = __logf(contrib) + esum;
    atomicAdd(out, (fwd - gold[b]) * (1.0f / 64.0f));
  }
}

extern "C" void kernel_launch(void* const* d_in, const int* in_sizes, int n_in,
                              void* d_out, int out_size, void* d_ws, size_t ws_size,
                              hipStream_t stream) {
  (void)in_sizes; (void)n_in; (void)out_size; (void)ws_size;
  const float* feat  = (const float*)d_in[0];
  const float* W     = (const float*)d_in[1];
  const float* bias  = (const float*)d_in[2];
  const float* trans = (const float*)d_in[3];
  const float* masks = (const float*)d_in[4];
  const int*   tags  = (const int*)d_in[5];

  char* ws = (char*)d_ws;
  float*  emit   = (float*)(ws + WS_EMIT);
  float*  chunks = (float*)(ws + WS_CHUNK);
  __bf16* wbf    = (__bf16*)(ws + WS_WBF);
  float*  gold   = (float*)(ws + WS_GOLD);
  float*  cexp   = (float*)(ws + WS_CEXP);

  hipMemsetAsync(d_out, 0, sizeof(float), stream);
  k_prep<<<HP, 256, 0, stream>>>(W, wbf);
  k_emit<<<(BB * TT) / 64, 256, 0, stream>>>(feat, wbf, bias, emit);
  k_gold<<<BB, 256, 0, stream>>>(emit, tags, masks, trans, gold);
  k_chunks<<<(BB * NCH) / 4, 256, 0, stream>>>(emit, trans, masks, chunks, cexp);
  k_combine<<<BB, 64, 0, stream>>>(chunks, cexp, trans, gold, (float*)d_out);
}

// Round 3
// 270.497 us; speedup vs baseline: 1.1038x; 1.0385x over previous
//
#include <hip/hip_runtime.h>
#include <hip/hip_bf16.h>
#include <math.h>

// CRF loss on MI355X — fused version.
//   k_prep:    W fp32 -> bf16 (padded 52->64), zero gold[]
//   k_scan:    per-wave fused: emit GEMM (32x64x1024 bf16 MFMA, feat->bf16
//              inline, emit tile -> wave-private LDS) + gold partial (atomic)
//              + 32-step forward-scan transfer-matrix product (bf16 MFMA)
//   k_combine: 16 sequential 64x64 matvecs per batch (double-buffered reg
//              prefetch) + last-tag gold term + atomic mean into d_out
//
// Scan math: P <- diag(exp(emit_t - (7+r)ln2)) * exp(Tpad) * P per step;
// exp(Tpad) is a constant MFMA A-operand in regs; fixed 2^-7/step shift folded
// into the exp arg + exact power-of-2 rescale every 8 steps; integer exponent
// accumulated. Padding: Tpad[i][j>=52]=NEG (exp->0), Tpad[i>=52][j<52]=0
// (finite pad rows, excluded at the end by exp(TSTOP[j>=52])=0).
// All LDS buffers are wave-private and accessed in program order -> NO
// __syncthreads anywhere in k_scan.

#define NEGV   (-100000000.0f)
#define BB     64
#define TT     512
#define FF     1024
#define HH     52
#define HP     64
#define S_START 50
#define S_STOP  51
#define NCH    16            // chunks per batch
#define CLEN   (TT / NCH)    // 32 steps per chunk

typedef __bf16 bf16x8 __attribute__((ext_vector_type(8)));
typedef __bf16 bf16x4 __attribute__((ext_vector_type(4)));
typedef float  f32x4  __attribute__((ext_vector_type(4)));

// ---------------- ws layout (bytes) ----------------
#define WS_CHUNK  0u           // fp32 [1024][16][64][4] (jj,i,jr)  16,777,216
#define WS_WBF    16777216u    // bf16 [HP][FF]                       131,072
#define WS_GOLD   16908288u    // fp32 [BB]
#define WS_CEXP   16908544u    // fp32 [1024]

// ---- W fp32 -> bf16 (pad rows 52..63 = 0); block 0 also zeroes gold ----
__global__ __launch_bounds__(256) void k_prep(const float* __restrict__ W,
                                              __bf16* __restrict__ wbf,
                                              float* __restrict__ gold) {
  int n = blockIdx.x;  // 0..63
  if (n == 0 && threadIdx.x < BB) gold[threadIdx.x] = 0.0f;
  for (int k = threadIdx.x; k < FF; k += 256) {
    float v = (n < HH) ? W[n * FF + k] : 0.0f;
    wbf[n * FF + k] = (__bf16)v;
  }
}

// ---- fused GEMM + gold partial + scan: 256 blocks x 4 waves = 1024 chunks ----
__global__ __launch_bounds__(256, 1) void k_scan(const float* __restrict__ feat,
                                                 const __bf16* __restrict__ wbf,
                                                 const float* __restrict__ bias,
                                                 const float* __restrict__ trans,
                                                 const float* __restrict__ masks,
                                                 const int* __restrict__ tags,
                                                 float* __restrict__ chunks,
                                                 float* __restrict__ cexp,
                                                 float* __restrict__ gold) {
  const int tid = threadIdx.x;
  const int wv = tid >> 6;
  const int l  = tid & 63;
  const int lm = l & 15;
  const int q  = l >> 4;
  const int chunk = blockIdx.x * 4 + wv;   // 0..1023
  const int b = chunk >> 4, c = chunk & 15;

  __shared__ __align__(16) __bf16 PTall[4][64 * 72];   // 36,864 B
  __shared__ __align__(16) float  Eall[4][CLEN * 64];  // 32,768 B
  __bf16* pt = PTall[wv];
  float*  el = Eall[wv];

  // ================= emit GEMM: M=32 (t), N=64 (state), K=1024 =================
  const float* fbase = feat + ((size_t)(b * TT + c * CLEN)) * FF;

  // A prefetch, 2 stages deep: apre[stage][mt2][half]
  f32x4 apre[2][2][2];
#pragma unroll
  for (int s = 0; s < 2; ++s)
#pragma unroll
    for (int mt2 = 0; mt2 < 2; ++mt2)
#pragma unroll
      for (int h = 0; h < 2; ++h)
        apre[s][mt2][h] = *(const f32x4*)(fbase + (size_t)(mt2 * 16 + lm) * FF + s * 32 + q * 8 + h * 4);

  bf16x8 bcur[4];
#pragma unroll
  for (int nt = 0; nt < 4; ++nt)
    bcur[nt] = *(const bf16x8*)(wbf + (size_t)(nt * 16 + lm) * FF + q * 8);

  f32x4 acc[2][4] = {};

#pragma unroll
  for (int kt = 0; kt < 32; ++kt) {
    const int st = kt & 1;
    bf16x8 af[2];
#pragma unroll
    for (int mt2 = 0; mt2 < 2; ++mt2)
#pragma unroll
      for (int j = 0; j < 4; ++j) {
        af[mt2][j]     = (__bf16)apre[st][mt2][0][j];
        af[mt2][4 + j] = (__bf16)apre[st][mt2][1][j];
      }
    if (kt + 2 < 32) {
      const float* fa = fbase + (kt + 2) * 32 + q * 8;
#pragma unroll
      for (int mt2 = 0; mt2 < 2; ++mt2)
#pragma unroll
        for (int h = 0; h < 2; ++h)
          apre[st][mt2][h] = *(const f32x4*)(fa + (size_t)(mt2 * 16 + lm) * FF + h * 4);
    }
    bf16x8 bnx[4];
    if (kt + 1 < 32) {
#pragma unroll
      for (int nt = 0; nt < 4; ++nt)
        bnx[nt] = *(const bf16x8*)(wbf + (size_t)(nt * 16 + lm) * FF + (kt + 1) * 32 + q * 8);
    }
#pragma unroll
    for (int mt2 = 0; mt2 < 2; ++mt2)
#pragma unroll
      for (int nt = 0; nt < 4; ++nt)
        acc[mt2][nt] = __builtin_amdgcn_mfma_f32_16x16x32_bf16(af[mt2], bcur[nt], acc[mt2][nt], 0, 0, 0);
    if (kt + 1 < 32) {
#pragma unroll
      for (int nt = 0; nt < 4; ++nt) bcur[nt] = bnx[nt];
    }
  }

  // epilogue -> LDS emit tile: el[t*64 + state]
#pragma unroll
  for (int nt = 0; nt < 4; ++nt) {
    int n = nt * 16 + lm;
    float bn = (n < HH) ? bias[n] : 0.0f;
#pragma unroll
    for (int mt2 = 0; mt2 < 2; ++mt2)
#pragma unroll
      for (int rr = 0; rr < 4; ++rr)
        el[(mt2 * 16 + q * 4 + rr) * 64 + n] = acc[mt2][nt][rr] + bn;  // D: row=q*4+rr, col=lm
  }

  // ================= gold partial for this chunk =================
  float mreg = (l < CLEN) ? masks[b * TT + c * CLEN + l] : 1.0f;
  int cur = (l < CLEN) ? tags[b * TT + c * CLEN + l] : 0;
  int prev = __shfl_up(cur, 1);
  if (l == 0) prev = (c == 0) ? S_START : tags[b * TT + c * CLEN - 1];
  float gp = 0.0f;
  if (l < CLEN) {
    float e  = el[l * 64 + cur];
    float tr = trans[cur * HH + prev];
    gp = (e + tr) * mreg;
  }
#pragma unroll
  for (int d = 1; d < 64; d <<= 1) gp += __shfl_xor(gp, d);
  if (l == 0) atomicAdd(&gold[b], gp);

  // ================= scan =================
  // constant A = exp(Tpad): 4 m-tiles x 2 k-chunks in regs
  bf16x8 afrag[4][2];
#pragma unroll
  for (int mt = 0; mt < 4; ++mt)
#pragma unroll
    for (int kk = 0; kk < 2; ++kk)
#pragma unroll
      for (int j = 0; j < 8; ++j) {
        int m = mt * 16 + lm, k = kk * 32 + q * 8 + j;
        float tv = (k >= HH) ? NEGV : ((m >= HH) ? 0.0f : trans[m * HH + k]);
        afrag[mt][kk][j] = (__bf16)__expf(tv);
      }

  // P = I (wave-private; in-order LDS -> no barriers)
  for (int idx = l; idx < 4096; idx += 64) {
    int n = idx >> 6, mm = idx & 63;
    pt[n * 72 + mm] = (__bf16)((n == mm) ? 1.0f : 0.0f);
  }

  int eacc = 0, rpend = 0;
  const float LOG2E = 1.4426950408889634f;

  for (int t = 0; t < CLEN; ++t) {
    float mcur = __shfl(mreg, t);             // wave-uniform
    if (mcur != 0.0f) {
      float sh = (float)(7 + rpend);
      eacc += 7 + rpend;
      rpend = 0;
      float s[4][4];
#pragma unroll
      for (int mt = 0; mt < 4; ++mt) {
        f32x4 em = *(const f32x4*)&el[t * 64 + mt * 16 + q * 4];
#pragma unroll
        for (int rr = 0; rr < 4; ++rr)
          s[mt][rr] = __builtin_amdgcn_exp2f(fmaf(em[rr], LOG2E, -sh));
      }

      // ALL reads before ALL writes (in-order LDS per wave)
      bf16x8 bfr[2][4];
#pragma unroll
      for (int kk = 0; kk < 2; ++kk)
#pragma unroll
        for (int nt = 0; nt < 4; ++nt)
          bfr[kk][nt] = *(const bf16x8*)&pt[(nt * 16 + lm) * 72 + kk * 32 + q * 8];

      const bool trk = ((t & 7) == 7) && (t != CLEN - 1);
      float lmax = 0.0f;
      f32x4 zero = {};
#pragma unroll
      for (int mt = 0; mt < 4; ++mt) {
#pragma unroll
        for (int nt = 0; nt < 4; ++nt) {
          f32x4 a = __builtin_amdgcn_mfma_f32_16x16x32_bf16(afrag[mt][0], bfr[0][nt], zero, 0, 0, 0);
          a = __builtin_amdgcn_mfma_f32_16x16x32_bf16(afrag[mt][1], bfr[1][nt], a, 0, 0, 0);
          bf16x4 w4;
#pragma unroll
          for (int rr = 0; rr < 4; ++rr) {
            float v = a[rr] * s[mt][rr];
            if (trk) lmax = fmaxf(lmax, v);
            w4[rr] = (__bf16)v;
          }
          *(bf16x4*)&pt[(nt * 16 + lm) * 72 + mt * 16 + q * 4] = w4;
        }
      }
      if (trk) {
#pragma unroll
        for (int d = 1; d < 64; d <<= 1) lmax = fmaxf(lmax, __shfl_xor(lmax, d));
        rpend = ilogbf(lmax);
      }
    }
  }

  // dump: chunks[chunk][jj*256 + i*4 + jr] = P[i][4jj+jr]
  for (int idx = l; idx < 4096; idx += 64) {
    int jj = idx >> 8, i = (idx >> 2) & 63, jr = idx & 3;
    chunks[(size_t)chunk * 4096 + idx] = (float)pt[(jj * 4 + jr) * 72 + i];
  }
  if (l == 0) cexp[chunk] = (float)eacc;
}

// ---- combine: 64 blocks x 1 wave; double-buffered matvec chain ----
__global__ __launch_bounds__(64) void k_combine(const float* __restrict__ chunks,
                                                const float* __restrict__ cexp,
                                                const float* __restrict__ trans,
                                                const float* __restrict__ masks,
                                                const int* __restrict__ tags,
                                                const float* __restrict__ gold,
                                                float* __restrict__ out) {
  const int b = blockIdx.x;
  const int l = threadIdx.x;   // 0..63 = state i
  __shared__ float vsh[64];
  float v = (l == S_START) ? 1.0f : 0.0f;
  float esum = 0.0f;
  const float LN2 = 0.6931471805599453f;

  // mask sum for the last-tag term (overlaps with matvec latency)
  float msum = 0.0f;
  for (int t = l; t < TT; t += 64) msum += masks[b * TT + t];

  f32x4 mb[2][16];
  {
    const f32x4* M = (const f32x4*)(chunks + ((size_t)(b * NCH)) * 4096);
#pragma unroll
    for (int jj = 0; jj < 16; ++jj) mb[0][jj] = M[jj * 64 + l];
  }

#pragma unroll
  for (int cc = 0; cc < NCH; ++cc) {
    vsh[l] = v;
    __syncthreads();
    if (cc + 1 < NCH) {
      const f32x4* Mn = (const f32x4*)(chunks + ((size_t)(b * NCH + cc + 1)) * 4096);
#pragma unroll
      for (int jj = 0; jj < 16; ++jj) mb[(cc + 1) & 1][jj] = Mn[jj * 64 + l];
    }
    f32x4 u4 = {};
#pragma unroll
    for (int jj = 0; jj < 16; ++jj) {
      f32x4 m4 = mb[cc & 1][jj];
      const float* vj = &vsh[jj * 4];
      u4[0] += m4[0] * vj[0];
      u4[1] += m4[1] * vj[1];
      u4[2] += m4[2] * vj[2];
      u4[3] += m4[3] * vj[3];
    }
    float u = (u4[0] + u4[1]) + (u4[2] + u4[3]);
    esum += cexp[b * NCH + cc] * LN2;
    float mxx = u;
#pragma unroll
    for (int d = 1; d < 64; d <<= 1) mxx = fmaxf(mxx, __shfl_xor(mxx, d));
    if (mxx > 0.0f) {
      int ee = ilogbf(mxx);
      u = ldexpf(u, -ee);
      esum += (float)ee * LN2;
    }
    v = u;
    __syncthreads();
  }

  float ts = (l < HH) ? trans[S_STOP * HH + l] : NEGV;  // exp(NEG)=0 excludes pads
  float contrib = v * __expf(ts);
#pragma unroll
  for (int d = 1; d < 64; d <<= 1) {
    contrib += __shfl_xor(contrib, d);
    msum += __shfl_xor(msum, d);
  }
  if (l == 0) {
    int lp = (int)(msum + 0.5f);
    int lt = (lp == 0) ? S_START : tags[b * TT + lp - 1];
    float goldb = gold[b] + trans[S_STOP * HH + lt];
    float fwd = __logf(contrib) + esum;
    atomicAdd(out, (fwd - goldb) * (1.0f / 64.0f));
  }
}

extern "C" void kernel_launch(void* const* d_in, const int* in_sizes, int n_in,
                              void* d_out, int out_size, void* d_ws, size_t ws_size,
                              hipStream_t stream) {
  (void)in_sizes; (void)n_in; (void)out_size; (void)ws_size;
  const float* feat  = (const float*)d_in[0];
  const float* W     = (const float*)d_in[1];
  const float* bias  = (const float*)d_in[2];
  const float* trans = (const float*)d_in[3];
  const float* masks = (const float*)d_in[4];
  const int*   tags  = (const int*)d_in[5];

  char* ws = (char*)d_ws;
  float*  chunks = (float*)(ws + WS_CHUNK);
  __bf16* wbf    = (__bf16*)(ws + WS_WBF);
  float*  gold   = (float*)(ws + WS_GOLD);
  float*  cexp   = (float*)(ws + WS_CEXP);

  hipMemsetAsync(d_out, 0, sizeof(float), stream);
  k_prep<<<HP, 256, 0, stream>>>(W, wbf, gold);
  k_scan<<<(BB * NCH) / 4, 256, 0, stream>>>(feat, wbf, bias, trans, masks, tags,
                                             chunks, cexp, gold);
  k_combine<<<BB, 64, 0, stream>>>(chunks, cexp, trans, masks, tags, gold, (float*)d_out);
}

// Round 4
// 262.479 us; speedup vs baseline: 1.1376x; 1.0305x over previous
//
#include <hip/hip_runtime.h>
#include <hip/hip_bf16.h>
#include <math.h>

// CRF loss on MI355X — fused, occupancy-doubled version.
//   k_prep:    W fp32->bf16 (pad 52->64), expT = exp(Tpad) bf16 [64][64], zero gold
//   k_scan:    per-wave fused: emit GEMM (16x64x1024 bf16 MFMA, 4-deep A prefetch)
//              -> bf16 emit tile in wave-private LDS -> gold partial (atomic)
//              -> 16-step transfer-matrix product (bf16 MFMA, no barriers)
//   k_combine: 32 sequential 64x64 matvecs per batch + last-tag term + atomic mean
//
// Scan math: P <- diag(exp(emit_t - (7+r)ln2)) * exp(Tpad) * P; exp(Tpad) is a
// constant MFMA A-operand (loaded from precomputed expT); fixed 2^-7/step shift
// folded into the exp arg + exact power-of-2 rescale at t==7; integer exponent
// accumulated. Padding: Tpad[i][j>=52]=NEG (exp->0), Tpad[i>=52][j<52]=0
// (finite pad rows, excluded at the end by exp(TSTOP[j>=52])=0).
// All LDS is wave-private, accessed in program order -> NO __syncthreads in k_scan.
// Occupancy: 2048 wave-chunks / 512 blocks / 2 blocks/CU = 8 waves/CU (R3 had 4).

#define NEGV   (-100000000.0f)
#define BB     64
#define TT     512
#define FF     1024
#define HH     52
#define HP     64
#define S_START 50
#define S_STOP  51
#define NCH    32            // chunks per batch
#define CLEN   (TT / NCH)    // 16 steps per chunk

typedef __bf16 bf16x8 __attribute__((ext_vector_type(8)));
typedef __bf16 bf16x4 __attribute__((ext_vector_type(4)));
typedef float  f32x4  __attribute__((ext_vector_type(4)));

// ---------------- ws layout (bytes) ----------------
#define WS_CHUNK  0u           // fp32 [2048][4096]               33,554,432
#define WS_WBF    33554432u    // bf16 [HP][FF]                      131,072
#define WS_EXPT   33685504u    // bf16 [64][64]                        8,192
#define WS_GOLD   33693696u    // fp32 [BB]
#define WS_CEXP   33693952u    // fp32 [2048]

// ---- W fp32 -> bf16 (pad rows 52..63 = 0); block 0: gold=0 and expT ----
__global__ __launch_bounds__(256) void k_prep(const float* __restrict__ W,
                                              const float* __restrict__ trans,
                                              __bf16* __restrict__ wbf,
                                              __bf16* __restrict__ expT,
                                              float* __restrict__ gold) {
  int n = blockIdx.x;  // 0..63
  if (n == 0) {
    if (threadIdx.x < BB) gold[threadIdx.x] = 0.0f;
    for (int idx = threadIdx.x; idx < 4096; idx += 256) {
      int m = idx >> 6, k = idx & 63;
      float tv = (k >= HH) ? NEGV : ((m >= HH) ? 0.0f : trans[m * HH + k]);
      expT[idx] = (__bf16)__expf(tv);
    }
  }
  for (int k = threadIdx.x; k < FF; k += 256) {
    float v = (n < HH) ? W[n * FF + k] : 0.0f;
    wbf[n * FF + k] = (__bf16)v;
  }
}

// ---- fused GEMM + gold partial + scan: 512 blocks x 4 waves = 2048 chunks ----
__global__ __launch_bounds__(256, 2) void k_scan(const float* __restrict__ feat,
                                                 const __bf16* __restrict__ wbf,
                                                 const __bf16* __restrict__ expT,
                                                 const float* __restrict__ bias,
                                                 const float* __restrict__ trans,
                                                 const float* __restrict__ masks,
                                                 const int* __restrict__ tags,
                                                 float* __restrict__ chunks,
                                                 float* __restrict__ cexp,
                                                 float* __restrict__ gold) {
  const int tid = threadIdx.x;
  const int wv = tid >> 6;
  const int l  = tid & 63;
  const int lm = l & 15;
  const int q  = l >> 4;
  const int chunk = blockIdx.x * 4 + wv;   // 0..2047
  const int b = chunk >> 5, c = chunk & 31;

  __shared__ __align__(16) __bf16 PTall[4][64 * 72];   // 36,864 B
  __shared__ __align__(16) __bf16 Eall[4][CLEN * 64];  //  8,192 B
  __bf16* pt = PTall[wv];
  __bf16* el = Eall[wv];

  // ================= emit GEMM: M=16 (t), N=64 (state), K=1024 =================
  const float* fbase = feat + ((size_t)(b * TT + c * CLEN)) * FF;
  const float* arow  = fbase + (size_t)lm * FF + q * 8;

  // A prefetch, 4 k-chunks deep (32 B/lane per k-chunk)
  f32x4 apre[4][2];
#pragma unroll
  for (int s = 0; s < 4; ++s)
#pragma unroll
    for (int h = 0; h < 2; ++h)
      apre[s][h] = *(const f32x4*)(arow + s * 32 + h * 4);

  bf16x8 bcur[4];
#pragma unroll
  for (int nt = 0; nt < 4; ++nt)
    bcur[nt] = *(const bf16x8*)(wbf + (size_t)(nt * 16 + lm) * FF + q * 8);

  f32x4 acc[4] = {};

#pragma unroll
  for (int kt = 0; kt < 32; ++kt) {
    const int st = kt & 3;
    bf16x8 af;
#pragma unroll
    for (int j = 0; j < 4; ++j) {
      af[j]     = (__bf16)apre[st][0][j];
      af[4 + j] = (__bf16)apre[st][1][j];
    }
    if (kt + 4 < 32) {
#pragma unroll
      for (int h = 0; h < 2; ++h)
        apre[st][h] = *(const f32x4*)(arow + (kt + 4) * 32 + h * 4);
    }
    bf16x8 bnx[4];
    if (kt + 1 < 32) {
#pragma unroll
      for (int nt = 0; nt < 4; ++nt)
        bnx[nt] = *(const bf16x8*)(wbf + (size_t)(nt * 16 + lm) * FF + (kt + 1) * 32 + q * 8);
    }
#pragma unroll
    for (int nt = 0; nt < 4; ++nt)
      acc[nt] = __builtin_amdgcn_mfma_f32_16x16x32_bf16(af, bcur[nt], acc[nt], 0, 0, 0);
    if (kt + 1 < 32) {
#pragma unroll
      for (int nt = 0; nt < 4; ++nt) bcur[nt] = bnx[nt];
    }
  }

  // epilogue -> LDS emit tile (bf16): el[t*64 + state]; D: row=q*4+rr, col=lm
#pragma unroll
  for (int nt = 0; nt < 4; ++nt) {
    int n = nt * 16 + lm;
    float bn = (n < HH) ? bias[n] : 0.0f;
#pragma unroll
    for (int rr = 0; rr < 4; ++rr)
      el[(q * 4 + rr) * 64 + n] = (__bf16)(acc[nt][rr] + bn);
  }

  // ================= gold partial for this chunk =================
  float mreg = (l < CLEN) ? masks[b * TT + c * CLEN + l] : 1.0f;
  int cur = (l < CLEN) ? tags[b * TT + c * CLEN + l] : 0;
  int prev = __shfl_up(cur, 1);
  if (l == 0) prev = (c == 0) ? S_START : tags[b * TT + c * CLEN - 1];
  float gp = 0.0f;
  if (l < CLEN) {
    float e  = (float)el[l * 64 + cur];
    float tr = trans[cur * HH + prev];
    gp = (e + tr) * mreg;
  }
#pragma unroll
  for (int d = 1; d < 64; d <<= 1) gp += __shfl_xor(gp, d);
  if (l == 0) atomicAdd(&gold[b], gp);

  // ================= scan =================
  // constant A = exp(Tpad) from precomputed table: 8 vector loads
  bf16x8 afrag[4][2];
#pragma unroll
  for (int mt = 0; mt < 4; ++mt)
#pragma unroll
    for (int kk = 0; kk < 2; ++kk)
      afrag[mt][kk] = *(const bf16x8*)&expT[(mt * 16 + lm) * 64 + kk * 32 + q * 8];

  // P = I (wave-private; in-order LDS -> no barriers)
  for (int idx = l; idx < 4096; idx += 64) {
    int n = idx >> 6, mm = idx & 63;
    pt[n * 72 + mm] = (__bf16)((n == mm) ? 1.0f : 0.0f);
  }

  int eacc = 0, rpend = 0;
  const float LOG2E = 1.4426950408889634f;

  for (int t = 0; t < CLEN; ++t) {
    float mcur = __shfl(mreg, t);             // wave-uniform
    if (mcur != 0.0f) {
      float sh = (float)(7 + rpend);
      eacc += 7 + rpend;
      rpend = 0;
      float s[4][4];
#pragma unroll
      for (int mt = 0; mt < 4; ++mt) {
        bf16x4 em4 = *(const bf16x4*)&el[t * 64 + mt * 16 + q * 4];
#pragma unroll
        for (int rr = 0; rr < 4; ++rr)
          s[mt][rr] = __builtin_amdgcn_exp2f(fmaf((float)em4[rr], LOG2E, -sh));
      }

      // ALL reads before ALL writes (in-order LDS per wave)
      bf16x8 bfr[2][4];
#pragma unroll
      for (int kk = 0; kk < 2; ++kk)
#pragma unroll
        for (int nt = 0; nt < 4; ++nt)
          bfr[kk][nt] = *(const bf16x8*)&pt[(nt * 16 + lm) * 72 + kk * 32 + q * 8];

      const bool trk = ((t & 7) == 7) && (t != CLEN - 1);
      float lmax = 0.0f;
      f32x4 zero = {};
#pragma unroll
      for (int mt = 0; mt < 4; ++mt) {
#pragma unroll
        for (int nt = 0; nt < 4; ++nt) {
          f32x4 a = __builtin_amdgcn_mfma_f32_16x16x32_bf16(afrag[mt][0], bfr[0][nt], zero, 0, 0, 0);
          a = __builtin_amdgcn_mfma_f32_16x16x32_bf16(afrag[mt][1], bfr[1][nt], a, 0, 0, 0);
          bf16x4 w4;
#pragma unroll
          for (int rr = 0; rr < 4; ++rr) {
            float v = a[rr] * s[mt][rr];
            if (trk) lmax = fmaxf(lmax, v);
            w4[rr] = (__bf16)v;
          }
          *(bf16x4*)&pt[(nt * 16 + lm) * 72 + mt * 16 + q * 4] = w4;
        }
      }
      if (trk) {
#pragma unroll
        for (int d = 1; d < 64; d <<= 1) lmax = fmaxf(lmax, __shfl_xor(lmax, d));
        rpend = ilogbf(lmax);
      }
    }
  }

  // dump: chunks[chunk][jj*256 + i*4 + jr] = P[i][4jj+jr]  (f32x4 coalesced)
  f32x4* c4 = (f32x4*)(chunks + (size_t)chunk * 4096);
#pragma unroll
  for (int it = 0; it < 16; ++it) {
    f32x4 v;
#pragma unroll
    for (int jr = 0; jr < 4; ++jr) v[jr] = (float)pt[(it * 4 + jr) * 72 + l];
    c4[it * 64 + l] = v;
  }
  if (l == 0) cexp[chunk] = (float)eacc;
}

// ---- combine: 64 blocks x 1 wave; double-buffered matvec chain (32 chunks) ----
__global__ __launch_bounds__(64) void k_combine(const float* __restrict__ chunks,
                                                const float* __restrict__ cexp,
                                                const float* __restrict__ trans,
                                                const float* __restrict__ masks,
                                                const int* __restrict__ tags,
                                                const float* __restrict__ gold,
                                                float* __restrict__ out) {
  const int b = blockIdx.x;
  const int l = threadIdx.x;   // 0..63 = state i
  __shared__ float vsh[64];
  float v = (l == S_START) ? 1.0f : 0.0f;
  float esum = 0.0f;
  const float LN2 = 0.6931471805599453f;

  float msum = 0.0f;
  for (int t = l; t < TT; t += 64) msum += masks[b * TT + t];

  f32x4 mb[2][16];
  {
    const f32x4* M = (const f32x4*)(chunks + ((size_t)(b * NCH)) * 4096);
#pragma unroll
    for (int jj = 0; jj < 16; ++jj) mb[0][jj] = M[jj * 64 + l];
  }

#pragma unroll
  for (int cc = 0; cc < NCH; ++cc) {
    vsh[l] = v;
    __syncthreads();
    if (cc + 1 < NCH) {
      const f32x4* Mn = (const f32x4*)(chunks + ((size_t)(b * NCH + cc + 1)) * 4096);
#pragma unroll
      for (int jj = 0; jj < 16; ++jj) mb[(cc + 1) & 1][jj] = Mn[jj * 64 + l];
    }
    f32x4 u4 = {};
#pragma unroll
    for (int jj = 0; jj < 16; ++jj) {
      f32x4 m4 = mb[cc & 1][jj];
      const float* vj = &vsh[jj * 4];
      u4[0] += m4[0] * vj[0];
      u4[1] += m4[1] * vj[1];
      u4[2] += m4[2] * vj[2];
      u4[3] += m4[3] * vj[3];
    }
    float u = (u4[0] + u4[1]) + (u4[2] + u4[3]);
    esum += cexp[b * NCH + cc] * LN2;
    float mxx = u;
#pragma unroll
    for (int d = 1; d < 64; d <<= 1) mxx = fmaxf(mxx, __shfl_xor(mxx, d));
    if (mxx > 0.0f) {
      int ee = ilogbf(mxx);
      u = ldexpf(u, -ee);
      esum += (float)ee * LN2;
    }
    v = u;
    __syncthreads();
  }

  float ts = (l < HH) ? trans[S_STOP * HH + l] : NEGV;  // exp(NEG)=0 excludes pads
  float contrib = v * __expf(ts);
#pragma unroll
  for (int d = 1; d < 64; d <<= 1) {
    contrib += __shfl_xor(contrib, d);
    msum += __shfl_xor(msum, d);
  }
  if (l == 0) {
    int lp = (int)(msum + 0.5f);
    int lt = (lp == 0) ? S_START : tags[b * TT + lp - 1];
    float goldb = gold[b] + trans[S_STOP * HH + lt];
    float fwd = __logf(contrib) + esum;
    atomicAdd(out, (fwd - goldb) * (1.0f / 64.0f));
  }
}

extern "C" void kernel_launch(void* const* d_in, const int* in_sizes, int n_in,
                              void* d_out, int out_size, void* d_ws, size_t ws_size,
                              hipStream_t stream) {
  (void)in_sizes; (void)n_in; (void)out_size; (void)ws_size;
  const float* feat  = (const float*)d_in[0];
  const float* W     = (const float*)d_in[1];
  const float* bias  = (const float*)d_in[2];
  const float* trans = (const float*)d_in[3];
  const float* masks = (const float*)d_in[4];
  const int*   tags  = (const int*)d_in[5];

  char* ws = (char*)d_ws;
  float*  chunks = (float*)(ws + WS_CHUNK);
  __bf16* wbf    = (__bf16*)(ws + WS_WBF);
  __bf16* expT   = (__bf16*)(ws + WS_EXPT);
  float*  gold   = (float*)(ws + WS_GOLD);
  float*  cexp   = (float*)(ws + WS_CEXP);

  hipMemsetAsync(d_out, 0, sizeof(float), stream);
  k_prep<<<HP, 256, 0, stream>>>(W, trans, wbf, expT, gold);
  k_scan<<<(BB * NCH) / 4, 256, 0, stream>>>(feat, wbf, expT, bias, trans, masks,
                                             tags, chunks, cexp, gold);
  k_combine<<<BB, 64, 0, stream>>>(chunks, cexp, trans, masks, tags, gold, (float*)d_out);
}